// Round 1
// baseline (1226.621 us; speedup 1.0000x reference)
//
#include <hip/hip_runtime.h>
#include <hip/hip_bf16.h>

// Problem constants
#define ROWS  16384            // B*npoints rows
#define KNB   64               // neighbors per row
#define PTOT  (ROWS * KNB)     // 1,048,576 positions
#define C0    67
#define NTOTF 1048576.0f
#define EPSF  1e-5f

__device__ __forceinline__ float relu_f(float x) { return x > 0.f ? x : 0.f; }

// ---------------------------------------------------------------------------
// K1: conv0  X[P][67] (fp32) -> H[P][64] (bf16), accumulate stats0 (sum, sumsq)
// grid = PTOT/128 blocks, 256 threads; tile = 128 positions
// ---------------------------------------------------------------------------
__global__ __launch_bounds__(256) void k_conv0(
    const float* __restrict__ X, const float* __restrict__ w0,
    const float* __restrict__ b0,
    __hip_bfloat16* __restrict__ H, float* __restrict__ stats)
{
    __shared__ float Xs[128 * 68];   // padded to 68, pad col zeroed
    __shared__ float Ws[64 * 68];
    __shared__ float red[256];
    const int tid = threadIdx.x;
    const int p0 = blockIdx.x * 128;

    // zero the pad column (disjoint elements from the fills below -> no race)
    if (tid < 128) Xs[tid * 68 + 67] = 0.f;
    else if (tid < 192) Ws[(tid - 128) * 68 + 67] = 0.f;
    for (int i = tid; i < 64 * 67; i += 256)
        Ws[(i / 67) * 68 + (i % 67)] = w0[i];
    for (int i = tid; i < 128 * 67; i += 256)
        Xs[(i / 67) * 68 + (i % 67)] = X[(size_t)p0 * 67 + i];
    __syncthreads();

    const int o  = tid & 63;   // output channel
    const int pg = tid >> 6;   // position group (wave-uniform)
    float4 wr[17];
#pragma unroll
    for (int q = 0; q < 17; ++q) wr[q] = *(const float4*)&Ws[o * 68 + 4 * q];
    const float bias = b0[o];

    float s = 0.f, s2 = 0.f;
    for (int j = 0; j < 8; ++j) {
        const int plb = pg * 32 + j * 4;
        float acc[4];
        acc[0] = bias; acc[1] = bias; acc[2] = bias; acc[3] = bias;
#pragma unroll
        for (int q = 0; q < 17; ++q) {
#pragma unroll
            for (int u = 0; u < 4; ++u) {
                const float4 xv = *(const float4*)&Xs[(plb + u) * 68 + 4 * q];
                acc[u] += xv.x * wr[q].x;
                acc[u] += xv.y * wr[q].y;
                acc[u] += xv.z * wr[q].z;
                acc[u] += xv.w * wr[q].w;
            }
        }
#pragma unroll
        for (int u = 0; u < 4; ++u) {
            H[(size_t)(p0 + plb + u) * 64 + o] = __float2bfloat16(acc[u]);
            s  += acc[u];
            s2 += acc[u] * acc[u];
        }
    }
    red[tid] = s; __syncthreads();
    if (tid < 64)
        unsafeAtomicAdd(&stats[tid], red[tid] + red[tid + 64] + red[tid + 128] + red[tid + 192]);
    __syncthreads();
    red[tid] = s2; __syncthreads();
    if (tid < 64)
        unsafeAtomicAdd(&stats[64 + tid], red[tid] + red[tid + 64] + red[tid + 128] + red[tid + 192]);
}

// ---------------------------------------------------------------------------
// K2: finalize BN0 (per block, cheap), y0 = relu(bn(H)), conv1 64->64,
// write H in place (bf16), accumulate stats1.
// ---------------------------------------------------------------------------
__global__ __launch_bounds__(256) void k_conv1(
    __hip_bfloat16* __restrict__ H, const float* __restrict__ w1,
    const float* __restrict__ b1,
    const float* __restrict__ g0, const float* __restrict__ be0,
    float* __restrict__ stats)
{
    __shared__ float Ys[128 * 64];
    __shared__ float als[64], bls[64];
    __shared__ float red[256];
    const int tid = threadIdx.x;
    if (tid < 64) {
        const float mean = stats[tid] * (1.f / NTOTF);
        const float var  = stats[64 + tid] * (1.f / NTOTF) - mean * mean;
        const float a    = g0[tid] / sqrtf(var + EPSF);
        als[tid] = a;
        bls[tid] = be0[tid] - mean * a;
    }
    __syncthreads();

    const int p0 = blockIdx.x * 128;
    const __hip_bfloat162* H2 = (const __hip_bfloat162*)H + (size_t)p0 * 32;
    for (int ii = tid; ii < 128 * 32; ii += 256) {
        const int c0 = (2 * ii) & 63;
        const float2 hv = __bfloat1622float2(H2[ii]);
        Ys[2 * ii]     = relu_f(als[c0] * hv.x + bls[c0]);
        Ys[2 * ii + 1] = relu_f(als[c0 + 1] * hv.y + bls[c0 + 1]);
    }
    __syncthreads();

    const int o  = tid & 63;
    const int pg = tid >> 6;
    float4 wr[16];
#pragma unroll
    for (int q = 0; q < 16; ++q) wr[q] = *(const float4*)&w1[o * 64 + 4 * q];
    const float bias = b1[o];

    float s = 0.f, s2 = 0.f;
    for (int j = 0; j < 8; ++j) {
        const int plb = pg * 32 + j * 4;
        float acc[4];
        acc[0] = bias; acc[1] = bias; acc[2] = bias; acc[3] = bias;
#pragma unroll
        for (int q = 0; q < 16; ++q) {
#pragma unroll
            for (int u = 0; u < 4; ++u) {
                const float4 xv = *(const float4*)&Ys[(plb + u) * 64 + 4 * q];
                acc[u] += xv.x * wr[q].x;
                acc[u] += xv.y * wr[q].y;
                acc[u] += xv.z * wr[q].z;
                acc[u] += xv.w * wr[q].w;
            }
        }
#pragma unroll
        for (int u = 0; u < 4; ++u) {
            H[(size_t)(p0 + plb + u) * 64 + o] = __float2bfloat16(acc[u]);
            s  += acc[u];
            s2 += acc[u] * acc[u];
        }
    }
    red[tid] = s; __syncthreads();
    if (tid < 64)
        unsafeAtomicAdd(&stats[128 + tid], red[tid] + red[tid + 64] + red[tid + 128] + red[tid + 192]);
    __syncthreads();
    red[tid] = s2; __syncthreads();
    if (tid < 64)
        unsafeAtomicAdd(&stats[192 + tid], red[tid] + red[tid + 64] + red[tid + 128] + red[tid + 192]);
}

// ---------------------------------------------------------------------------
// K3: finalize BN1, y1 = relu(bn(H)), conv2 64->128; per-row max AND min of
// pre-BN conv2 output (max_k relu(a*h+b) == relu(a*max_k h + b) for a>0,
// min for a<0); accumulate stats2 over ALL h2 values on the fly.
// grid = ROWS/2 blocks (2 rows = 128 positions per block).
// ---------------------------------------------------------------------------
__global__ __launch_bounds__(256) void k_conv2(
    const __hip_bfloat16* __restrict__ H, const float* __restrict__ w2,
    const float* __restrict__ b2,
    const float* __restrict__ g1, const float* __restrict__ be1,
    float* __restrict__ rowmax, float* __restrict__ rowmin,
    float* __restrict__ stats)
{
    __shared__ float Ys[128 * 64];
    __shared__ float als[64], bls[64];
    __shared__ float red[256];
    const int tid = threadIdx.x;
    if (tid < 64) {
        const float mean = stats[128 + tid] * (1.f / NTOTF);
        const float var  = stats[192 + tid] * (1.f / NTOTF) - mean * mean;
        const float a    = g1[tid] / sqrtf(var + EPSF);
        als[tid] = a;
        bls[tid] = be1[tid] - mean * a;
    }
    __syncthreads();

    const int r0 = blockIdx.x * 2;
    const int p0 = r0 * 64;
    const __hip_bfloat162* H2 = (const __hip_bfloat162*)H + (size_t)p0 * 32;
    for (int ii = tid; ii < 128 * 32; ii += 256) {
        const int c0 = (2 * ii) & 63;
        const float2 hv = __bfloat1622float2(H2[ii]);
        Ys[2 * ii]     = relu_f(als[c0] * hv.x + bls[c0]);
        Ys[2 * ii + 1] = relu_f(als[c0 + 1] * hv.y + bls[c0 + 1]);
    }
    __syncthreads();

    const int o  = tid & 127;  // output channel 0..127
    const int rh = tid >> 7;   // which of the 2 rows (wave-uniform)
    float4 wr[16];
#pragma unroll
    for (int q = 0; q < 16; ++q) wr[q] = *(const float4*)&w2[o * 64 + 4 * q];
    const float bias = b2[o];

    float mx = -3.4e38f, mn = 3.4e38f, s = 0.f, s2 = 0.f;
    for (int k = 0; k < 64; ++k) {
        const float* yrow = &Ys[(rh * 64 + k) * 64];
        float ax = 0.f, ay = 0.f, az = 0.f, aw = 0.f;
#pragma unroll
        for (int q = 0; q < 16; ++q) {
            const float4 xv = *(const float4*)&yrow[4 * q];
            ax += xv.x * wr[q].x;
            ay += xv.y * wr[q].y;
            az += xv.z * wr[q].z;
            aw += xv.w * wr[q].w;
        }
        const float acc = bias + ((ax + ay) + (az + aw));
        mx = fmaxf(mx, acc);
        mn = fminf(mn, acc);
        s  += acc;
        s2 += acc * acc;
    }
    rowmax[(size_t)(r0 + rh) * 128 + o] = mx;
    rowmin[(size_t)(r0 + rh) * 128 + o] = mn;

    red[tid] = s; __syncthreads();
    if (tid < 128) unsafeAtomicAdd(&stats[256 + tid], red[tid] + red[tid + 128]);
    __syncthreads();
    red[tid] = s2; __syncthreads();
    if (tid < 128) unsafeAtomicAdd(&stats[384 + tid], red[tid] + red[tid + 128]);
}

// ---------------------------------------------------------------------------
// K4: finalize BN2 + epilogue: out[r][o] = relu(a2*(a2>0 ? rowmax : rowmin) + b2)
// ---------------------------------------------------------------------------
__global__ __launch_bounds__(256) void k_out(
    const float* __restrict__ rowmax, const float* __restrict__ rowmin,
    const float* __restrict__ g2, const float* __restrict__ be2,
    const float* __restrict__ stats, float* __restrict__ out)
{
    __shared__ float als[128], bls[128];
    const int tid = threadIdx.x;
    if (tid < 128) {
        const float mean = stats[256 + tid] * (1.f / NTOTF);
        const float var  = stats[384 + tid] * (1.f / NTOTF) - mean * mean;
        const float a    = g2[tid] / sqrtf(var + EPSF);
        als[tid] = a;
        bls[tid] = be2[tid] - mean * a;
    }
    __syncthreads();
    const int idx = blockIdx.x * 256 + tid;
    const int o = idx & 127;
    const float a = als[o];
    const float v = (a > 0.f) ? rowmax[idx] : rowmin[idx];
    out[idx] = relu_f(a * v + bls[o]);
}

// ---------------------------------------------------------------------------
extern "C" void kernel_launch(void* const* d_in, const int* in_sizes, int n_in,
                              void* d_out, int out_size, void* d_ws, size_t ws_size,
                              hipStream_t stream)
{
    (void)in_sizes; (void)n_in; (void)out_size; (void)ws_size;
    const float* X   = (const float*)d_in[0];
    const float* w0  = (const float*)d_in[1];
    const float* b0  = (const float*)d_in[2];
    const float* g0  = (const float*)d_in[3];
    const float* be0 = (const float*)d_in[4];
    const float* w1  = (const float*)d_in[5];
    const float* b1  = (const float*)d_in[6];
    const float* g1  = (const float*)d_in[7];
    const float* be1 = (const float*)d_in[8];
    const float* w2  = (const float*)d_in[9];
    const float* b2  = (const float*)d_in[10];
    const float* g2  = (const float*)d_in[11];
    const float* be2 = (const float*)d_in[12];
    float* out = (float*)d_out;

    // workspace layout
    char* ws = (char*)d_ws;
    __hip_bfloat16* H = (__hip_bfloat16*)ws;                 // PTOT*64*2 = 134,217,728 B
    float* rowmax = (float*)(ws + 134217728);                // ROWS*128*4 = 8,388,608 B
    float* rowmin = (float*)(ws + 134217728 + 8388608);      // 8,388,608 B
    float* stats  = (float*)(ws + 134217728 + 2 * 8388608);  // 512 floats
    // stats: [0:64) sum0, [64:128) sq0, [128:192) sum1, [192:256) sq1,
    //        [256:384) sum2, [384:512) sq2

    hipMemsetAsync(stats, 0, 512 * sizeof(float), stream);
    hipLaunchKernelGGL(k_conv0, dim3(PTOT / 128), dim3(256), 0, stream, X, w0, b0, H, stats);
    hipLaunchKernelGGL(k_conv1, dim3(PTOT / 128), dim3(256), 0, stream, H, w1, b1, g0, be0, stats);
    hipLaunchKernelGGL(k_conv2, dim3(ROWS / 2), dim3(256), 0, stream, H, w2, b2, g1, be1, rowmax, rowmin, stats);
    hipLaunchKernelGGL(k_out, dim3(ROWS * 128 / 256), dim3(256), 0, stream, rowmax, rowmin, g2, be2, stats, out);
}

// Round 2
// 961.789 us; speedup vs baseline: 1.2754x; 1.2754x over previous
//
#include <hip/hip_runtime.h>
#include <hip/hip_bf16.h>

#define ROWS  16384
#define PTOT  1048576
#define NTOTF 1048576.0f
#define EPSF  1e-5f

typedef __attribute__((ext_vector_type(8))) short short8;   // 8 bf16 = 4 VGPRs (MFMA A/B frag)
typedef __attribute__((ext_vector_type(4))) float floatx4;  // MFMA C/D frag

union FU { float f; unsigned int u; };

__device__ __forceinline__ float bfbits2f(unsigned short s) {
    FU fu; fu.u = ((unsigned int)s) << 16; return fu.f;
}
__device__ __forceinline__ unsigned short f2bfbits(float x) {
    FU fu; fu.f = x;
    unsigned int r = fu.u + 0x7FFFu + ((fu.u >> 16) & 1u);  // RNE
    return (unsigned short)(r >> 16);
}
__device__ __forceinline__ float relu_f(float x) { return x > 0.f ? x : 0.f; }

// ---------------------------------------------------------------------------
// K1: conv0  X[P][67] fp32 -> H[P][64] bf16 via MFMA (K padded 67->96),
// stats0 (sum, sumsq). Tile: 128 positions. 4 waves, 2 m-tiles each.
// ---------------------------------------------------------------------------
__global__ __launch_bounds__(256) void k_conv0(
    const float* __restrict__ X, const float* __restrict__ w0,
    const float* __restrict__ b0, unsigned short* __restrict__ H,
    float* __restrict__ stats)
{
    __shared__ unsigned short Ys[128 * 104];  // bf16 X tile, K padded to 96, stride 104
    __shared__ unsigned short Hs[128 * 72];   // bf16 output staging, stride 72
    __shared__ float sred[64], s2red[64];
    const int tid  = threadIdx.x;
    const int lane = tid & 63;
    const int wid  = tid >> 6;
    const int ln15 = lane & 15;
    const int quad = lane >> 4;
    const int p0   = blockIdx.x * 128;

    if (tid < 64) { sred[tid] = 0.f; s2red[tid] = 0.f; }

    // stage X (fp32, float4-vectorized: 128*67 = 8576 floats = 2144 float4)
    {
        const float4* Xv = (const float4*)(X + (size_t)p0 * 67);
        for (int i = tid; i < 2144; i += 256) {
            float4 x = Xv[i];
            int e = 4 * i;
            int r = e / 67;
            int c = e - 67 * r;
            float v[4] = {x.x, x.y, x.z, x.w};
#pragma unroll
            for (int j = 0; j < 4; ++j) {
                Ys[r * 104 + c] = f2bfbits(v[j]);
                if (++c == 67) { c = 0; ++r; }
            }
        }
        for (int i = tid; i < 128 * 29; i += 256) {  // zero K-pad cols 67..95
            int r = i / 29, c = i - 29 * r;
            Ys[r * 104 + 67 + c] = 0;
        }
    }

    // B fragments: B[k][n] = w0[n][k]; lane: n = nt*16 + ln15, k = ks*32 + quad*8 + j
    short8 bfr[12];
    float bias[4];
#pragma unroll
    for (int nt = 0; nt < 4; ++nt) {
        const int n = nt * 16 + ln15;
        bias[nt] = b0[n];
#pragma unroll
        for (int ks = 0; ks < 3; ++ks) {
            short8 v;
#pragma unroll
            for (int j = 0; j < 8; ++j) {
                const int k = ks * 32 + quad * 8 + j;
                const float w = (k < 67) ? w0[n * 67 + k] : 0.f;
                v[j] = (short)f2bfbits(w);
            }
            bfr[nt * 3 + ks] = v;
        }
    }
    __syncthreads();

    float s[4] = {0, 0, 0, 0}, s2[4] = {0, 0, 0, 0};
#pragma unroll
    for (int mi = 0; mi < 2; ++mi) {
        const int mt  = wid * 2 + mi;
        const int row = mt * 16 + ln15;
        short8 afr[3];
#pragma unroll
        for (int ks = 0; ks < 3; ++ks)
            afr[ks] = *reinterpret_cast<const short8*>(&Ys[row * 104 + ks * 32 + quad * 8]);
#pragma unroll
        for (int nt = 0; nt < 4; ++nt) {
            floatx4 a = {0.f, 0.f, 0.f, 0.f};
#pragma unroll
            for (int ks = 0; ks < 3; ++ks)
                a = __builtin_amdgcn_mfma_f32_16x16x32_bf16(afr[ks], bfr[nt * 3 + ks], a, 0, 0, 0);
#pragma unroll
            for (int rg = 0; rg < 4; ++rg) {
                const float h = a[rg] + bias[nt];
                s[nt] += h; s2[nt] += h * h;
                const int orow = mt * 16 + quad * 4 + rg;  // C: row=(lane>>4)*4+rg, col=ln15
                Hs[orow * 72 + nt * 16 + ln15] = f2bfbits(h);
            }
        }
    }
#pragma unroll
    for (int nt = 0; nt < 4; ++nt) {
        s[nt]  += __shfl_xor(s[nt], 16, 64);  s[nt]  += __shfl_xor(s[nt], 32, 64);
        s2[nt] += __shfl_xor(s2[nt], 16, 64); s2[nt] += __shfl_xor(s2[nt], 32, 64);
    }
    if (lane < 16) {
#pragma unroll
        for (int nt = 0; nt < 4; ++nt) {
            atomicAdd(&sred[nt * 16 + ln15], s[nt]);
            atomicAdd(&s2red[nt * 16 + ln15], s2[nt]);
        }
    }
    __syncthreads();
    if (tid < 64) {
        unsafeAtomicAdd(&stats[tid], sred[tid]);
        unsafeAtomicAdd(&stats[64 + tid], s2red[tid]);
    }
    // coalesced bf16 store: 128 rows x 8 chunks of 16 B
#pragma unroll
    for (int it = 0; it < 4; ++it) {
        const int idx = it * 256 + tid;
        const int r = idx >> 3, c8 = idx & 7;
        short8 v = *reinterpret_cast<const short8*>(&Hs[r * 72 + c8 * 8]);
        *reinterpret_cast<short8*>(&H[(size_t)(p0 + r) * 64 + c8 * 8]) = v;
    }
}

// ---------------------------------------------------------------------------
// K2: finalize BN0, y0 = relu(bn(H0)), conv1 64->64 via MFMA, H1 in place,
// stats1.
// ---------------------------------------------------------------------------
__global__ __launch_bounds__(256) void k_conv1(
    unsigned short* __restrict__ H, const float* __restrict__ w1,
    const float* __restrict__ b1, const float* __restrict__ g0,
    const float* __restrict__ be0, float* __restrict__ stats)
{
    __shared__ unsigned short Ys[128 * 72];
    __shared__ unsigned short Hs[128 * 72];
    __shared__ float als[64], bls[64];
    __shared__ float sred[64], s2red[64];
    const int tid  = threadIdx.x;
    const int lane = tid & 63;
    const int wid  = tid >> 6;
    const int ln15 = lane & 15;
    const int quad = lane >> 4;
    const int p0   = blockIdx.x * 128;

    if (tid < 64) {
        const float mean = stats[tid] * (1.f / NTOTF);
        const float var  = stats[64 + tid] * (1.f / NTOTF) - mean * mean;
        const float a    = g0[tid] / sqrtf(var + EPSF);
        als[tid] = a; bls[tid] = be0[tid] - mean * a;
        sred[tid] = 0.f; s2red[tid] = 0.f;
    }
    __syncthreads();

    // stage H0 -> y0 (BN+relu) -> LDS bf16, stride 72
#pragma unroll
    for (int it = 0; it < 4; ++it) {
        const int idx = it * 256 + tid;
        const int r = idx >> 3, c8 = idx & 7;
        short8 v = *reinterpret_cast<const short8*>(&H[(size_t)(p0 + r) * 64 + c8 * 8]);
        short8 o;
#pragma unroll
        for (int j = 0; j < 8; ++j) {
            const int c = c8 * 8 + j;
            o[j] = (short)f2bfbits(relu_f(als[c] * bfbits2f((unsigned short)v[j]) + bls[c]));
        }
        *reinterpret_cast<short8*>(&Ys[r * 72 + c8 * 8]) = o;
    }

    short8 bfr[8];
    float bias[4];
#pragma unroll
    for (int nt = 0; nt < 4; ++nt) {
        const int n = nt * 16 + ln15;
        bias[nt] = b1[n];
#pragma unroll
        for (int ks = 0; ks < 2; ++ks) {
            const float4* wp = (const float4*)&w1[n * 64 + ks * 32 + quad * 8];
            float4 w0v = wp[0], w1v = wp[1];
            short8 v;
            v[0] = (short)f2bfbits(w0v.x); v[1] = (short)f2bfbits(w0v.y);
            v[2] = (short)f2bfbits(w0v.z); v[3] = (short)f2bfbits(w0v.w);
            v[4] = (short)f2bfbits(w1v.x); v[5] = (short)f2bfbits(w1v.y);
            v[6] = (short)f2bfbits(w1v.z); v[7] = (short)f2bfbits(w1v.w);
            bfr[nt * 2 + ks] = v;
        }
    }
    __syncthreads();

    float s[4] = {0, 0, 0, 0}, s2[4] = {0, 0, 0, 0};
#pragma unroll
    for (int mi = 0; mi < 2; ++mi) {
        const int mt  = wid * 2 + mi;
        const int row = mt * 16 + ln15;
        short8 a0 = *reinterpret_cast<const short8*>(&Ys[row * 72 + quad * 8]);
        short8 a1 = *reinterpret_cast<const short8*>(&Ys[row * 72 + 32 + quad * 8]);
#pragma unroll
        for (int nt = 0; nt < 4; ++nt) {
            floatx4 a = {0.f, 0.f, 0.f, 0.f};
            a = __builtin_amdgcn_mfma_f32_16x16x32_bf16(a0, bfr[nt * 2 + 0], a, 0, 0, 0);
            a = __builtin_amdgcn_mfma_f32_16x16x32_bf16(a1, bfr[nt * 2 + 1], a, 0, 0, 0);
#pragma unroll
            for (int rg = 0; rg < 4; ++rg) {
                const float h = a[rg] + bias[nt];
                s[nt] += h; s2[nt] += h * h;
                const int orow = mt * 16 + quad * 4 + rg;
                Hs[orow * 72 + nt * 16 + ln15] = f2bfbits(h);
            }
        }
    }
#pragma unroll
    for (int nt = 0; nt < 4; ++nt) {
        s[nt]  += __shfl_xor(s[nt], 16, 64);  s[nt]  += __shfl_xor(s[nt], 32, 64);
        s2[nt] += __shfl_xor(s2[nt], 16, 64); s2[nt] += __shfl_xor(s2[nt], 32, 64);
    }
    if (lane < 16) {
#pragma unroll
        for (int nt = 0; nt < 4; ++nt) {
            atomicAdd(&sred[nt * 16 + ln15], s[nt]);
            atomicAdd(&s2red[nt * 16 + ln15], s2[nt]);
        }
    }
    __syncthreads();
    if (tid < 64) {
        unsafeAtomicAdd(&stats[128 + tid], sred[tid]);
        unsafeAtomicAdd(&stats[192 + tid], s2red[tid]);
    }
#pragma unroll
    for (int it = 0; it < 4; ++it) {
        const int idx = it * 256 + tid;
        const int r = idx >> 3, c8 = idx & 7;
        short8 v = *reinterpret_cast<const short8*>(&Hs[r * 72 + c8 * 8]);
        *reinterpret_cast<short8*>(&H[(size_t)(p0 + r) * 64 + c8 * 8]) = v;
    }
}

// ---------------------------------------------------------------------------
// K3: finalize BN1, y1 = relu(bn(H1)), conv2 64->128 via MFMA; per point-row
// max/min of pre-BN h2 (monotone BN+relu trick) + stats2. Never stores H2.
// Tile: 2 point-rows (128 positions). Wave w: point-row w>>1, channels (w&1)*64.
// ---------------------------------------------------------------------------
__global__ __launch_bounds__(256) void k_conv2(
    const unsigned short* __restrict__ H, const float* __restrict__ w2,
    const float* __restrict__ b2, const float* __restrict__ g1,
    const float* __restrict__ be1, float* __restrict__ rowmax,
    float* __restrict__ rowmin, float* __restrict__ stats)
{
    __shared__ unsigned short Ys[128 * 72];
    __shared__ float als[64], bls[64];
    __shared__ float sred[128], s2red[128];
    const int tid  = threadIdx.x;
    const int lane = tid & 63;
    const int wid  = tid >> 6;
    const int ln15 = lane & 15;
    const int quad = lane >> 4;
    const int p0   = blockIdx.x * 128;
    const int r0   = blockIdx.x * 2;

    if (tid < 64) {
        const float mean = stats[128 + tid] * (1.f / NTOTF);
        const float var  = stats[192 + tid] * (1.f / NTOTF) - mean * mean;
        const float a    = g1[tid] / sqrtf(var + EPSF);
        als[tid] = a; bls[tid] = be1[tid] - mean * a;
    }
    if (tid < 128) { sred[tid] = 0.f; s2red[tid] = 0.f; }
    __syncthreads();

#pragma unroll
    for (int it = 0; it < 4; ++it) {
        const int idx = it * 256 + tid;
        const int r = idx >> 3, c8 = idx & 7;
        short8 v = *reinterpret_cast<const short8*>(&H[(size_t)(p0 + r) * 64 + c8 * 8]);
        short8 o;
#pragma unroll
        for (int j = 0; j < 8; ++j) {
            const int c = c8 * 8 + j;
            o[j] = (short)f2bfbits(relu_f(als[c] * bfbits2f((unsigned short)v[j]) + bls[c]));
        }
        *reinterpret_cast<short8*>(&Ys[r * 72 + c8 * 8]) = o;
    }

    const int pr     = wid >> 1;        // which point-row of the 2
    const int chHalf = (wid & 1) * 64;  // channel half 0..63 / 64..127
    short8 bfr[8];
    float bias[4];
#pragma unroll
    for (int nt = 0; nt < 4; ++nt) {
        const int n = chHalf + nt * 16 + ln15;
        bias[nt] = b2[n];
#pragma unroll
        for (int ks = 0; ks < 2; ++ks) {
            const float4* wp = (const float4*)&w2[n * 64 + ks * 32 + quad * 8];
            float4 w0v = wp[0], w1v = wp[1];
            short8 v;
            v[0] = (short)f2bfbits(w0v.x); v[1] = (short)f2bfbits(w0v.y);
            v[2] = (short)f2bfbits(w0v.z); v[3] = (short)f2bfbits(w0v.w);
            v[4] = (short)f2bfbits(w1v.x); v[5] = (short)f2bfbits(w1v.y);
            v[6] = (short)f2bfbits(w1v.z); v[7] = (short)f2bfbits(w1v.w);
            bfr[nt * 2 + ks] = v;
        }
    }
    __syncthreads();

    float mx[4] = {-3.4e38f, -3.4e38f, -3.4e38f, -3.4e38f};
    float mn[4] = {3.4e38f, 3.4e38f, 3.4e38f, 3.4e38f};
    float s[4] = {0, 0, 0, 0}, s2[4] = {0, 0, 0, 0};
#pragma unroll
    for (int mt = 0; mt < 4; ++mt) {
        const int row = pr * 64 + mt * 16 + ln15;
        short8 a0 = *reinterpret_cast<const short8*>(&Ys[row * 72 + quad * 8]);
        short8 a1 = *reinterpret_cast<const short8*>(&Ys[row * 72 + 32 + quad * 8]);
#pragma unroll
        for (int nt = 0; nt < 4; ++nt) {
            floatx4 a = {0.f, 0.f, 0.f, 0.f};
            a = __builtin_amdgcn_mfma_f32_16x16x32_bf16(a0, bfr[nt * 2 + 0], a, 0, 0, 0);
            a = __builtin_amdgcn_mfma_f32_16x16x32_bf16(a1, bfr[nt * 2 + 1], a, 0, 0, 0);
#pragma unroll
            for (int rg = 0; rg < 4; ++rg) {
                const float h = a[rg] + bias[nt];
                mx[nt] = fmaxf(mx[nt], h);
                mn[nt] = fminf(mn[nt], h);
                s[nt] += h; s2[nt] += h * h;
            }
        }
    }
#pragma unroll
    for (int nt = 0; nt < 4; ++nt) {
        mx[nt] = fmaxf(mx[nt], __shfl_xor(mx[nt], 16, 64));
        mx[nt] = fmaxf(mx[nt], __shfl_xor(mx[nt], 32, 64));
        mn[nt] = fminf(mn[nt], __shfl_xor(mn[nt], 16, 64));
        mn[nt] = fminf(mn[nt], __shfl_xor(mn[nt], 32, 64));
        s[nt]  += __shfl_xor(s[nt], 16, 64);  s[nt]  += __shfl_xor(s[nt], 32, 64);
        s2[nt] += __shfl_xor(s2[nt], 16, 64); s2[nt] += __shfl_xor(s2[nt], 32, 64);
    }
    if (lane < 16) {
#pragma unroll
        for (int nt = 0; nt < 4; ++nt) {
            const int c = chHalf + nt * 16 + lane;
            rowmax[(size_t)(r0 + pr) * 128 + c] = mx[nt];
            rowmin[(size_t)(r0 + pr) * 128 + c] = mn[nt];
            atomicAdd(&sred[c], s[nt]);
            atomicAdd(&s2red[c], s2[nt]);
        }
    }
    __syncthreads();
    if (tid < 128) {
        unsafeAtomicAdd(&stats[256 + tid], sred[tid]);
        unsafeAtomicAdd(&stats[384 + tid], s2red[tid]);
    }
}

// ---------------------------------------------------------------------------
// K4: finalize BN2 + epilogue
// ---------------------------------------------------------------------------
__global__ __launch_bounds__(256) void k_out(
    const float* __restrict__ rowmax, const float* __restrict__ rowmin,
    const float* __restrict__ g2, const float* __restrict__ be2,
    const float* __restrict__ stats, float* __restrict__ out)
{
    __shared__ float als[128], bls[128];
    const int tid = threadIdx.x;
    if (tid < 128) {
        const float mean = stats[256 + tid] * (1.f / NTOTF);
        const float var  = stats[384 + tid] * (1.f / NTOTF) - mean * mean;
        const float a    = g2[tid] / sqrtf(var + EPSF);
        als[tid] = a; bls[tid] = be2[tid] - mean * a;
    }
    __syncthreads();
    const int idx = blockIdx.x * 256 + tid;
    const int o = idx & 127;
    const float a = als[o];
    const float v = (a > 0.f) ? rowmax[idx] : rowmin[idx];
    out[idx] = relu_f(a * v + bls[o]);
}

// ---------------------------------------------------------------------------
extern "C" void kernel_launch(void* const* d_in, const int* in_sizes, int n_in,
                              void* d_out, int out_size, void* d_ws, size_t ws_size,
                              hipStream_t stream)
{
    (void)in_sizes; (void)n_in; (void)out_size; (void)ws_size;
    const float* X   = (const float*)d_in[0];
    const float* w0  = (const float*)d_in[1];
    const float* b0  = (const float*)d_in[2];
    const float* g0  = (const float*)d_in[3];
    const float* be0 = (const float*)d_in[4];
    const float* w1  = (const float*)d_in[5];
    const float* b1  = (const float*)d_in[6];
    const float* g1  = (const float*)d_in[7];
    const float* be1 = (const float*)d_in[8];
    const float* w2  = (const float*)d_in[9];
    const float* b2  = (const float*)d_in[10];
    const float* g2  = (const float*)d_in[11];
    const float* be2 = (const float*)d_in[12];
    float* out = (float*)d_out;

    char* ws = (char*)d_ws;
    unsigned short* H = (unsigned short*)ws;                 // PTOT*64*2 = 134,217,728 B
    float* rowmax = (float*)(ws + 134217728);                // ROWS*128*4 = 8,388,608 B
    float* rowmin = (float*)(ws + 134217728 + 8388608);      // 8,388,608 B
    float* stats  = (float*)(ws + 134217728 + 2 * 8388608);  // 512 floats
    // stats: [0:64) sum0, [64:128) sq0, [128:192) sum1, [192:256) sq1,
    //        [256:384) sum2, [384:512) sq2

    hipMemsetAsync(stats, 0, 512 * sizeof(float), stream);
    hipLaunchKernelGGL(k_conv0, dim3(PTOT / 128), dim3(256), 0, stream, X, w0, b0, H, stats);
    hipLaunchKernelGGL(k_conv1, dim3(PTOT / 128), dim3(256), 0, stream, H, w1, b1, g0, be0, stats);
    hipLaunchKernelGGL(k_conv2, dim3(ROWS / 2), dim3(256), 0, stream, H, w2, b2, g1, be1, rowmax, rowmin, stats);
    hipLaunchKernelGGL(k_out, dim3(ROWS * 128 / 256), dim3(256), 0, stream, rowmax, rowmin, g2, be2, stats, out);
}

// Round 3
// 758.374 us; speedup vs baseline: 1.6174x; 1.2682x over previous
//
#include <hip/hip_runtime.h>
#include <hip/hip_bf16.h>

#define ROWS  16384
#define PTOT  1048576
#define NTOTF 1048576.0f
#define EPSF  1e-5f

typedef __attribute__((ext_vector_type(8))) short short8;   // 8 bf16 (MFMA A/B frag)
typedef __attribute__((ext_vector_type(4))) float floatx4;  // MFMA C/D frag

union FU { float f; unsigned int u; };

__device__ __forceinline__ float bfbits2f(unsigned short s) {
    FU fu; fu.u = ((unsigned int)s) << 16; return fu.f;
}
__device__ __forceinline__ unsigned short f2bfbits(float x) {
    FU fu; fu.f = x;
    unsigned int r = fu.u + 0x7FFFu + ((fu.u >> 16) & 1u);  // RNE
    return (unsigned short)(r >> 16);
}
__device__ __forceinline__ float relu_f(float x) { return x > 0.f ? x : 0.f; }

// async global->LDS, 16 B per lane; lds dst = uniform base + lane*16
__device__ __forceinline__ void async16(const float4* g, float* l) {
    __builtin_amdgcn_global_load_lds(
        (const __attribute__((address_space(1))) void*)(g),
        (__attribute__((address_space(3))) void*)(l), 16, 0, 0);
}

// ---------------------------------------------------------------------------
// K1: conv0  X[P][67] fp32 -> H[P][64] bf16 via MFMA (K=64) + fp32 tail (3 ch),
// stats0. Tile 128 positions. X staged flat into LDS via global_load_lds;
// fp32->bf16 conversion at fragment-read time. Output staging aliases Xs.
// ---------------------------------------------------------------------------
__global__ __launch_bounds__(256) void k_conv0(
    const float* __restrict__ X, const float* __restrict__ w0,
    const float* __restrict__ b0, unsigned short* __restrict__ H,
    float* __restrict__ stats)
{
    __shared__ alignas(16) float Xs[128 * 67];   // 34,304 B flat fp32 tile
    __shared__ float sred[64], s2red[64];
    unsigned short* Hs = (unsigned short*)Xs;    // aliased after barrier (18,432 B)

    const int tid  = threadIdx.x;
    const int lane = tid & 63;
    const int wid  = tid >> 6;
    const int ln15 = lane & 15;
    const int quad = lane >> 4;
    const int p0   = blockIdx.x * 128;

    if (tid < 64) { sred[tid] = 0.f; s2red[tid] = 0.f; }

    // stage X flat: 2144 float4 chunks
    const float4* Xv = (const float4*)(X + (size_t)p0 * 67);
#pragma unroll
    for (int t = 0; t < 8; ++t)
        async16(&Xv[t * 256 + tid], &Xs[(t * 256 + wid * 64) * 4]);
    if (tid < 96)
        async16(&Xv[2048 + tid], &Xs[(2048 + wid * 64) * 4]);

    // B fragments (k<64) + tail weights (k=64..66) + bias
    short8 bfr[8];
    float wt[4][3], bias[4];
#pragma unroll
    for (int nt = 0; nt < 4; ++nt) {
        const int n = nt * 16 + ln15;
        bias[nt] = b0[n];
#pragma unroll
        for (int t = 0; t < 3; ++t) wt[nt][t] = w0[n * 67 + 64 + t];
#pragma unroll
        for (int ks = 0; ks < 2; ++ks) {
            short8 v;
#pragma unroll
            for (int j = 0; j < 8; ++j)
                v[j] = (short)f2bfbits(w0[n * 67 + ks * 32 + quad * 8 + j]);
            bfr[nt * 2 + ks] = v;
        }
    }
    __syncthreads();   // drains global_load_lds (vmcnt) + barrier

    float s[4] = {0, 0, 0, 0}, s2[4] = {0, 0, 0, 0};
    float hv[2][4][4];
#pragma unroll
    for (int mi = 0; mi < 2; ++mi) {
        const int mt = wid * 2 + mi;
        // A fragments: read fp32 from flat LDS, convert to bf16
        short8 a0, a1;
        {
            const float* xp = &Xs[(mt * 16 + ln15) * 67 + quad * 8];
#pragma unroll
            for (int j = 0; j < 8; ++j) a0[j] = (short)f2bfbits(xp[j]);
#pragma unroll
            for (int j = 0; j < 8; ++j) a1[j] = (short)f2bfbits(xp[32 + j]);
        }
        // tail inputs: X[p][64..66] for the 4 C-rows this lane owns
        float xt[4][3];
#pragma unroll
        for (int rg = 0; rg < 4; ++rg) {
            const float* tp = &Xs[(mt * 16 + quad * 4 + rg) * 67 + 64];
#pragma unroll
            for (int t = 0; t < 3; ++t) xt[rg][t] = tp[t];
        }
#pragma unroll
        for (int nt = 0; nt < 4; ++nt) {
            floatx4 a = {0.f, 0.f, 0.f, 0.f};
            a = __builtin_amdgcn_mfma_f32_16x16x32_bf16(a0, bfr[nt * 2 + 0], a, 0, 0, 0);
            a = __builtin_amdgcn_mfma_f32_16x16x32_bf16(a1, bfr[nt * 2 + 1], a, 0, 0, 0);
#pragma unroll
            for (int rg = 0; rg < 4; ++rg) {
                float h = a[rg] + bias[nt];
#pragma unroll
                for (int t = 0; t < 3; ++t) h += xt[rg][t] * wt[nt][t];
                hv[mi][nt][rg] = h;
                s[nt] += h; s2[nt] += h * h;
            }
        }
    }
    // stats reduce
#pragma unroll
    for (int nt = 0; nt < 4; ++nt) {
        s[nt]  += __shfl_xor(s[nt], 16, 64);  s[nt]  += __shfl_xor(s[nt], 32, 64);
        s2[nt] += __shfl_xor(s2[nt], 16, 64); s2[nt] += __shfl_xor(s2[nt], 32, 64);
    }
    if (lane < 16) {
#pragma unroll
        for (int nt = 0; nt < 4; ++nt) {
            atomicAdd(&sred[nt * 16 + ln15], s[nt]);
            atomicAdd(&s2red[nt * 16 + ln15], s2[nt]);
        }
    }
    __syncthreads();   // all Xs reads done -> safe to alias as Hs
#pragma unroll
    for (int mi = 0; mi < 2; ++mi) {
        const int mt = wid * 2 + mi;
#pragma unroll
        for (int nt = 0; nt < 4; ++nt)
#pragma unroll
            for (int rg = 0; rg < 4; ++rg)
                Hs[(mt * 16 + quad * 4 + rg) * 72 + nt * 16 + ln15] = f2bfbits(hv[mi][nt][rg]);
    }
    __syncthreads();
    if (tid < 64) {
        unsafeAtomicAdd(&stats[tid], sred[tid]);
        unsafeAtomicAdd(&stats[64 + tid], s2red[tid]);
    }
#pragma unroll
    for (int it = 0; it < 4; ++it) {
        const int idx = it * 256 + tid;
        const int r = idx >> 3, c8 = idx & 7;
        short8 v = *reinterpret_cast<const short8*>(&Hs[r * 72 + c8 * 8]);
        *reinterpret_cast<short8*>(&H[(size_t)(p0 + r) * 64 + c8 * 8]) = v;
    }
}

// ---------------------------------------------------------------------------
// K2: conv1 64->64. Barrier-free main loop: A-frags straight from global with
// BN0+relu applied in registers; per-wave private LDS repack for stores.
// Block 256 = 4 waves x 4 m-tiles = 256 positions. In-place H update.
// ---------------------------------------------------------------------------
__global__ __launch_bounds__(256) void k_conv1(
    unsigned short* H, const float* __restrict__ w1,
    const float* __restrict__ b1, const float* __restrict__ g0,
    const float* __restrict__ be0, float* __restrict__ stats)
{
    __shared__ float als[64], bls[64], sred[64], s2red[64];
    __shared__ alignas(16) unsigned short Hw[4 * 16 * 72];  // per-wave repack
    const int tid  = threadIdx.x;
    const int lane = tid & 63;
    const int wid  = tid >> 6;
    const int ln15 = lane & 15;
    const int quad = lane >> 4;
    const int pw0  = blockIdx.x * 256 + wid * 64;

    if (tid < 64) {
        const float mean = stats[tid] * (1.f / NTOTF);
        const float var  = stats[64 + tid] * (1.f / NTOTF) - mean * mean;
        const float a    = g0[tid] / sqrtf(var + EPSF);
        als[tid] = a; bls[tid] = be0[tid] - mean * a;
        sred[tid] = 0.f; s2red[tid] = 0.f;
    }
    __syncthreads();

    // per-lane BN coefficients for the 16 k-channels this lane touches
    float alr[16], blr[16];
#pragma unroll
    for (int ks = 0; ks < 2; ++ks)
#pragma unroll
        for (int j = 0; j < 8; ++j) {
            alr[ks * 8 + j] = als[ks * 32 + quad * 8 + j];
            blr[ks * 8 + j] = bls[ks * 32 + quad * 8 + j];
        }

    short8 bfr[8];
    float bias[4];
#pragma unroll
    for (int nt = 0; nt < 4; ++nt) {
        const int n = nt * 16 + ln15;
        bias[nt] = b1[n];
#pragma unroll
        for (int ks = 0; ks < 2; ++ks) {
            const float4* wp = (const float4*)&w1[n * 64 + ks * 32 + quad * 8];
            float4 wa = wp[0], wb = wp[1];
            short8 v;
            v[0] = (short)f2bfbits(wa.x); v[1] = (short)f2bfbits(wa.y);
            v[2] = (short)f2bfbits(wa.z); v[3] = (short)f2bfbits(wa.w);
            v[4] = (short)f2bfbits(wb.x); v[5] = (short)f2bfbits(wb.y);
            v[6] = (short)f2bfbits(wb.z); v[7] = (short)f2bfbits(wb.w);
            bfr[nt * 2 + ks] = v;
        }
    }

    unsigned short* hw = &Hw[wid * 16 * 72];
    float s[4] = {0, 0, 0, 0}, s2[4] = {0, 0, 0, 0};
    for (int mt = 0; mt < 4; ++mt) {
        const size_t rowb = (size_t)(pw0 + mt * 16 + ln15) * 64;
        const short8 h0 = *reinterpret_cast<const short8*>(&H[rowb + quad * 8]);
        const short8 h1 = *reinterpret_cast<const short8*>(&H[rowb + 32 + quad * 8]);
        short8 a0, a1;
#pragma unroll
        for (int j = 0; j < 8; ++j) {
            a0[j] = (short)f2bfbits(relu_f(alr[j] * bfbits2f((unsigned short)h0[j]) + blr[j]));
            a1[j] = (short)f2bfbits(relu_f(alr[8 + j] * bfbits2f((unsigned short)h1[j]) + blr[8 + j]));
        }
#pragma unroll
        for (int nt = 0; nt < 4; ++nt) {
            floatx4 a = {0.f, 0.f, 0.f, 0.f};
            a = __builtin_amdgcn_mfma_f32_16x16x32_bf16(a0, bfr[nt * 2 + 0], a, 0, 0, 0);
            a = __builtin_amdgcn_mfma_f32_16x16x32_bf16(a1, bfr[nt * 2 + 1], a, 0, 0, 0);
#pragma unroll
            for (int rg = 0; rg < 4; ++rg) {
                const float h = a[rg] + bias[nt];
                s[nt] += h; s2[nt] += h * h;
                hw[(quad * 4 + rg) * 72 + nt * 16 + ln15] = f2bfbits(h);
            }
        }
        // same-wave LDS: program order within the wave; no barrier needed
#pragma unroll
        for (int ps = 0; ps < 2; ++ps) {
            const int idx = ps * 64 + lane;
            const int r = idx >> 3, c8 = idx & 7;
            short8 v = *reinterpret_cast<const short8*>(&hw[r * 72 + c8 * 8]);
            *reinterpret_cast<short8*>(&H[(size_t)(pw0 + mt * 16 + r) * 64 + c8 * 8]) = v;
        }
    }
#pragma unroll
    for (int nt = 0; nt < 4; ++nt) {
        s[nt]  += __shfl_xor(s[nt], 16, 64);  s[nt]  += __shfl_xor(s[nt], 32, 64);
        s2[nt] += __shfl_xor(s2[nt], 16, 64); s2[nt] += __shfl_xor(s2[nt], 32, 64);
    }
    if (lane < 16) {
#pragma unroll
        for (int nt = 0; nt < 4; ++nt) {
            atomicAdd(&sred[nt * 16 + ln15], s[nt]);
            atomicAdd(&s2red[nt * 16 + ln15], s2[nt]);
        }
    }
    __syncthreads();
    if (tid < 64) {
        unsafeAtomicAdd(&stats[128 + tid], sred[tid]);
        unsafeAtomicAdd(&stats[192 + tid], s2red[tid]);
    }
}

// ---------------------------------------------------------------------------
// K3: conv2 64->128, barrier-free A-loads with BN1+relu in registers; per
// point-row max/min of pre-BN h2 + stats2; H2 never materialized.
// Block 256 = 4 waves; wave handles 2 point-rows x 64 channels.
// ---------------------------------------------------------------------------
__global__ __launch_bounds__(256) void k_conv2(
    const unsigned short* __restrict__ H, const float* __restrict__ w2,
    const float* __restrict__ b2, const float* __restrict__ g1,
    const float* __restrict__ be1, float* __restrict__ rowmax,
    float* __restrict__ rowmin, float* __restrict__ stats)
{
    __shared__ float als[64], bls[64], sred[128], s2red[128];
    const int tid  = threadIdx.x;
    const int lane = tid & 63;
    const int wid  = tid >> 6;
    const int ln15 = lane & 15;
    const int quad = lane >> 4;
    const int r0   = blockIdx.x * 4;

    if (tid < 64) {
        const float mean = stats[128 + tid] * (1.f / NTOTF);
        const float var  = stats[192 + tid] * (1.f / NTOTF) - mean * mean;
        const float a    = g1[tid] / sqrtf(var + EPSF);
        als[tid] = a; bls[tid] = be1[tid] - mean * a;
    }
    if (tid < 128) { sred[tid] = 0.f; s2red[tid] = 0.f; }
    __syncthreads();

    float alr[16], blr[16];
#pragma unroll
    for (int ks = 0; ks < 2; ++ks)
#pragma unroll
        for (int j = 0; j < 8; ++j) {
            alr[ks * 8 + j] = als[ks * 32 + quad * 8 + j];
            blr[ks * 8 + j] = bls[ks * 32 + quad * 8 + j];
        }

    const int chHalf = (wid & 1) * 64;
    short8 bfr[8];
    float bias[4];
#pragma unroll
    for (int nt = 0; nt < 4; ++nt) {
        const int n = chHalf + nt * 16 + ln15;
        bias[nt] = b2[n];
#pragma unroll
        for (int ks = 0; ks < 2; ++ks) {
            const float4* wp = (const float4*)&w2[n * 64 + ks * 32 + quad * 8];
            float4 wa = wp[0], wb = wp[1];
            short8 v;
            v[0] = (short)f2bfbits(wa.x); v[1] = (short)f2bfbits(wa.y);
            v[2] = (short)f2bfbits(wa.z); v[3] = (short)f2bfbits(wa.w);
            v[4] = (short)f2bfbits(wb.x); v[5] = (short)f2bfbits(wb.y);
            v[6] = (short)f2bfbits(wb.z); v[7] = (short)f2bfbits(wb.w);
            bfr[nt * 2 + ks] = v;
        }
    }

    float s[4] = {0, 0, 0, 0}, s2[4] = {0, 0, 0, 0};
    for (int rr = 0; rr < 2; ++rr) {
        const int prow = r0 + (wid >> 1) * 2 + rr;
        float mx[4] = {-3.4e38f, -3.4e38f, -3.4e38f, -3.4e38f};
        float mn[4] = {3.4e38f, 3.4e38f, 3.4e38f, 3.4e38f};
        for (int mt = 0; mt < 4; ++mt) {
            const size_t rowb = (size_t)(prow * 64 + mt * 16 + ln15) * 64;
            const short8 h0 = *reinterpret_cast<const short8*>(&H[rowb + quad * 8]);
            const short8 h1 = *reinterpret_cast<const short8*>(&H[rowb + 32 + quad * 8]);
            short8 a0, a1;
#pragma unroll
            for (int j = 0; j < 8; ++j) {
                a0[j] = (short)f2bfbits(relu_f(alr[j] * bfbits2f((unsigned short)h0[j]) + blr[j]));
                a1[j] = (short)f2bfbits(relu_f(alr[8 + j] * bfbits2f((unsigned short)h1[j]) + blr[8 + j]));
            }
#pragma unroll
            for (int nt = 0; nt < 4; ++nt) {
                floatx4 a = {0.f, 0.f, 0.f, 0.f};
                a = __builtin_amdgcn_mfma_f32_16x16x32_bf16(a0, bfr[nt * 2 + 0], a, 0, 0, 0);
                a = __builtin_amdgcn_mfma_f32_16x16x32_bf16(a1, bfr[nt * 2 + 1], a, 0, 0, 0);
#pragma unroll
                for (int rg = 0; rg < 4; ++rg) {
                    const float h = a[rg] + bias[nt];
                    mx[nt] = fmaxf(mx[nt], h);
                    mn[nt] = fminf(mn[nt], h);
                    s[nt] += h; s2[nt] += h * h;
                }
            }
        }
#pragma unroll
        for (int nt = 0; nt < 4; ++nt) {
            mx[nt] = fmaxf(mx[nt], __shfl_xor(mx[nt], 16, 64));
            mx[nt] = fmaxf(mx[nt], __shfl_xor(mx[nt], 32, 64));
            mn[nt] = fminf(mn[nt], __shfl_xor(mn[nt], 16, 64));
            mn[nt] = fminf(mn[nt], __shfl_xor(mn[nt], 32, 64));
        }
        if (lane < 16) {
#pragma unroll
            for (int nt = 0; nt < 4; ++nt) {
                rowmax[(size_t)prow * 128 + chHalf + nt * 16 + lane] = mx[nt];
                rowmin[(size_t)prow * 128 + chHalf + nt * 16 + lane] = mn[nt];
            }
        }
    }
#pragma unroll
    for (int nt = 0; nt < 4; ++nt) {
        s[nt]  += __shfl_xor(s[nt], 16, 64);  s[nt]  += __shfl_xor(s[nt], 32, 64);
        s2[nt] += __shfl_xor(s2[nt], 16, 64); s2[nt] += __shfl_xor(s2[nt], 32, 64);
    }
    if (lane < 16) {
#pragma unroll
        for (int nt = 0; nt < 4; ++nt) {
            atomicAdd(&sred[chHalf + nt * 16 + ln15], s[nt]);
            atomicAdd(&s2red[chHalf + nt * 16 + ln15], s2[nt]);
        }
    }
    __syncthreads();
    if (tid < 128) {
        unsafeAtomicAdd(&stats[256 + tid], sred[tid]);
        unsafeAtomicAdd(&stats[384 + tid], s2red[tid]);
    }
}

// ---------------------------------------------------------------------------
// K4: finalize BN2 + epilogue
// ---------------------------------------------------------------------------
__global__ __launch_bounds__(256) void k_out(
    const float* __restrict__ rowmax, const float* __restrict__ rowmin,
    const float* __restrict__ g2, const float* __restrict__ be2,
    const float* __restrict__ stats, float* __restrict__ out)
{
    __shared__ float als[128], bls[128];
    const int tid = threadIdx.x;
    if (tid < 128) {
        const float mean = stats[256 + tid] * (1.f / NTOTF);
        const float var  = stats[384 + tid] * (1.f / NTOTF) - mean * mean;
        const float a    = g2[tid] / sqrtf(var + EPSF);
        als[tid] = a; bls[tid] = be2[tid] - mean * a;
    }
    __syncthreads();
    const int idx = blockIdx.x * 256 + tid;
    const int o = idx & 127;
    const float a = als[o];
    const float v = (a > 0.f) ? rowmax[idx] : rowmin[idx];
    out[idx] = relu_f(a * v + bls[o]);
}

// ---------------------------------------------------------------------------
extern "C" void kernel_launch(void* const* d_in, const int* in_sizes, int n_in,
                              void* d_out, int out_size, void* d_ws, size_t ws_size,
                              hipStream_t stream)
{
    (void)in_sizes; (void)n_in; (void)out_size; (void)ws_size;
    const float* X   = (const float*)d_in[0];
    const float* w0  = (const float*)d_in[1];
    const float* b0  = (const float*)d_in[2];
    const float* g0  = (const float*)d_in[3];
    const float* be0 = (const float*)d_in[4];
    const float* w1  = (const float*)d_in[5];
    const float* b1  = (const float*)d_in[6];
    const float* g1  = (const float*)d_in[7];
    const float* be1 = (const float*)d_in[8];
    const float* w2  = (const float*)d_in[9];
    const float* b2  = (const float*)d_in[10];
    const float* g2  = (const float*)d_in[11];
    const float* be2 = (const float*)d_in[12];
    float* out = (float*)d_out;

    char* ws = (char*)d_ws;
    unsigned short* H = (unsigned short*)ws;                 // 134,217,728 B
    float* rowmax = (float*)(ws + 134217728);                // 8,388,608 B
    float* rowmin = (float*)(ws + 134217728 + 8388608);      // 8,388,608 B
    float* stats  = (float*)(ws + 134217728 + 2 * 8388608);  // 512 floats

    hipMemsetAsync(stats, 0, 512 * sizeof(float), stream);
    hipLaunchKernelGGL(k_conv0, dim3(PTOT / 128), dim3(256), 0, stream, X, w0, b0, H, stats);
    hipLaunchKernelGGL(k_conv1, dim3(PTOT / 256), dim3(256), 0, stream, H, w1, b1, g0, be0, stats);
    hipLaunchKernelGGL(k_conv2, dim3(ROWS / 4), dim3(256), 0, stream, H, w2, b2, g1, be1, rowmax, rowmin, stats);
    hipLaunchKernelGGL(k_out, dim3(ROWS * 128 / 256), dim3(256), 0, stream, rowmax, rowmin, g2, be2, stats, out);
}

// Round 4
// 602.404 us; speedup vs baseline: 2.0362x; 1.2589x over previous
//
#include <hip/hip_runtime.h>
#include <hip/hip_bf16.h>

#define ROWS  16384
#define PTOT  1048576
#define NTOTF 1048576.0f
#define EPSF  1e-5f
#define NREP  16                 // stats replication factor (atomic decontention)

typedef __attribute__((ext_vector_type(8))) short short8;   // 8 bf16 (MFMA A/B frag)
typedef __attribute__((ext_vector_type(4))) float floatx4;  // MFMA C/D frag
typedef float f32x4 __attribute__((ext_vector_type(4)));
typedef f32x4 f32x4u __attribute__((aligned(4)));           // 4B-aligned vector load

union FU { float f; unsigned int u; };

__device__ __forceinline__ float bfbits2f(unsigned short s) {
    FU fu; fu.u = ((unsigned int)s) << 16; return fu.f;
}
__device__ __forceinline__ unsigned short f2bfbits(float x) {
    FU fu; fu.f = x;
    unsigned int r = fu.u + 0x7FFFu + ((fu.u >> 16) & 1u);  // RNE
    return (unsigned short)(r >> 16);
}
__device__ __forceinline__ float relu_f(float x) { return x > 0.f ? x : 0.f; }

// ---------------------------------------------------------------------------
// K1: conv0  X[P][67] fp32 -> H[P][64] bf16.  Operand-swapped MFMA:
// A = w0 (m=outch, persistent), B = X positions (n=pos), K=67 as 2 full
// k-steps + tail fragment (cols 64..66, quad0 only; loaded via float4 at
// col 63, elem 0 discarded -> always in bounds).  No LDS staging, no
// barriers in the main loop; direct 8B stores (C row=channel!).
// Wave: 64 positions (4 n-tiles). Block 256 thr = 256 positions. Grid 4096.
// ---------------------------------------------------------------------------
__global__ __launch_bounds__(256) void k_conv0(
    const float* __restrict__ X, const float* __restrict__ w0,
    const float* __restrict__ b0, unsigned short* __restrict__ H,
    float* __restrict__ stats)
{
    __shared__ float sred[64], s2red[64];
    const int tid  = threadIdx.x;
    const int lane = tid & 63;
    const int wid  = tid >> 6;
    const int ln15 = lane & 15;
    const int quad = lane >> 4;
    const int pbase = blockIdx.x * 256 + wid * 64;

    if (tid < 64) { sred[tid] = 0.f; s2red[tid] = 0.f; }
    __syncthreads();

    // A-fragments: weights. m = mt*16+ln15, k = kh*32+quad*8+j (+ tail frag)
    short8 afr[4][3];
    floatx4 bias[4];
#pragma unroll
    for (int mt = 0; mt < 4; ++mt) {
        const float* wr = w0 + (size_t)(mt * 16 + ln15) * 67;
#pragma unroll
        for (int kh = 0; kh < 2; ++kh) {
            f32x4u wa = *reinterpret_cast<const f32x4u*>(wr + kh * 32 + quad * 8);
            f32x4u wb = *reinterpret_cast<const f32x4u*>(wr + kh * 32 + quad * 8 + 4);
            short8 v;
#pragma unroll
            for (int j = 0; j < 4; ++j) { v[j] = (short)f2bfbits(wa[j]); v[4 + j] = (short)f2bfbits(wb[j]); }
            afr[mt][kh] = v;
        }
        short8 t = {0, 0, 0, 0, 0, 0, 0, 0};
        if (quad == 0) {
            f32x4u tv = *reinterpret_cast<const f32x4u*>(wr + 63);  // cols 63..66
            t[0] = (short)f2bfbits(tv[1]); t[1] = (short)f2bfbits(tv[2]); t[2] = (short)f2bfbits(tv[3]);
        }
        afr[mt][2] = t;
        bias[mt] = *reinterpret_cast<const floatx4*>(b0 + mt * 16 + quad * 4);
    }

    float s[4][4] = {}, s2[4][4] = {};
#pragma unroll 2
    for (int nt = 0; nt < 4; ++nt) {
        const int pos = pbase + nt * 16 + ln15;
        const float* xr = X + (size_t)pos * 67;
        // B-fragments: n = ln15 (this position), k = kh*32+quad*8+j
        short8 bf0, bf1, bft = {0, 0, 0, 0, 0, 0, 0, 0};
        {
            f32x4u xa = *reinterpret_cast<const f32x4u*>(xr + quad * 8);
            f32x4u xb = *reinterpret_cast<const f32x4u*>(xr + quad * 8 + 4);
            f32x4u xc = *reinterpret_cast<const f32x4u*>(xr + 32 + quad * 8);
            f32x4u xd = *reinterpret_cast<const f32x4u*>(xr + 32 + quad * 8 + 4);
#pragma unroll
            for (int j = 0; j < 4; ++j) {
                bf0[j] = (short)f2bfbits(xa[j]); bf0[4 + j] = (short)f2bfbits(xb[j]);
                bf1[j] = (short)f2bfbits(xc[j]); bf1[4 + j] = (short)f2bfbits(xd[j]);
            }
            if (quad == 0) {
                f32x4u tv = *reinterpret_cast<const f32x4u*>(xr + 63);
                bft[0] = (short)f2bfbits(tv[1]); bft[1] = (short)f2bfbits(tv[2]); bft[2] = (short)f2bfbits(tv[3]);
            }
        }
#pragma unroll
        for (int mt = 0; mt < 4; ++mt) {
            floatx4 c = {0.f, 0.f, 0.f, 0.f};
            c = __builtin_amdgcn_mfma_f32_16x16x32_bf16(afr[mt][0], bf0, c, 0, 0, 0);
            c = __builtin_amdgcn_mfma_f32_16x16x32_bf16(afr[mt][1], bf1, c, 0, 0, 0);
            c = __builtin_amdgcn_mfma_f32_16x16x32_bf16(afr[mt][2], bft, c, 0, 0, 0);
            // C layout: row (=channel in tile) = quad*4+rg, col (=position) = ln15
            uint2 o;
            float h0 = c[0] + bias[mt][0], h1 = c[1] + bias[mt][1];
            float h2 = c[2] + bias[mt][2], h3 = c[3] + bias[mt][3];
            s[mt][0] += h0; s2[mt][0] += h0 * h0;
            s[mt][1] += h1; s2[mt][1] += h1 * h1;
            s[mt][2] += h2; s2[mt][2] += h2 * h2;
            s[mt][3] += h3; s2[mt][3] += h3 * h3;
            o.x = (unsigned int)f2bfbits(h0) | ((unsigned int)f2bfbits(h1) << 16);
            o.y = (unsigned int)f2bfbits(h2) | ((unsigned int)f2bfbits(h3) << 16);
            *reinterpret_cast<uint2*>(&H[(size_t)pos * 64 + mt * 16 + quad * 4]) = o;
        }
    }
    // stats: sum over positions = over ln15 lanes
#pragma unroll
    for (int mt = 0; mt < 4; ++mt)
#pragma unroll
        for (int rg = 0; rg < 4; ++rg) {
            s[mt][rg]  += __shfl_xor(s[mt][rg], 1, 64);  s[mt][rg]  += __shfl_xor(s[mt][rg], 2, 64);
            s[mt][rg]  += __shfl_xor(s[mt][rg], 4, 64);  s[mt][rg]  += __shfl_xor(s[mt][rg], 8, 64);
            s2[mt][rg] += __shfl_xor(s2[mt][rg], 1, 64); s2[mt][rg] += __shfl_xor(s2[mt][rg], 2, 64);
            s2[mt][rg] += __shfl_xor(s2[mt][rg], 4, 64); s2[mt][rg] += __shfl_xor(s2[mt][rg], 8, 64);
        }
    if (ln15 == 0) {
#pragma unroll
        for (int mt = 0; mt < 4; ++mt)
#pragma unroll
            for (int rg = 0; rg < 4; ++rg) {
                atomicAdd(&sred[mt * 16 + quad * 4 + rg], s[mt][rg]);
                atomicAdd(&s2red[mt * 16 + quad * 4 + rg], s2[mt][rg]);
            }
    }
    __syncthreads();
    const int rep = (blockIdx.x & (NREP - 1)) * 512;
    if (tid < 64) {
        unsafeAtomicAdd(&stats[rep + tid], sred[tid]);
        unsafeAtomicAdd(&stats[rep + 64 + tid], s2red[tid]);
    }
}

// ---------------------------------------------------------------------------
// K2: conv1 64->64. Same operand-swapped, barrier-free structure; BN0+relu
// applied in registers on the loaded H0 fragments. In-place H via two
// restrict pointers (per-tile loads strictly precede same-tile stores by
// data dependence; tiles are address-disjoint).
// ---------------------------------------------------------------------------
__global__ __launch_bounds__(256) void k_conv1(
    const unsigned short* __restrict__ Hin, unsigned short* __restrict__ Hout,
    const float* __restrict__ w1, const float* __restrict__ b1,
    const float* __restrict__ g0, const float* __restrict__ be0,
    float* __restrict__ stats)
{
    __shared__ float als[64], bls[64], sred[64], s2red[64];
    const int tid  = threadIdx.x;
    const int lane = tid & 63;
    const int wid  = tid >> 6;
    const int ln15 = lane & 15;
    const int quad = lane >> 4;
    const int pbase = blockIdx.x * 256 + wid * 64;

    if (tid < 64) {
        float ssum = 0.f, qsum = 0.f;
#pragma unroll
        for (int r = 0; r < NREP; ++r) { ssum += stats[r * 512 + tid]; qsum += stats[r * 512 + 64 + tid]; }
        const float mean = ssum * (1.f / NTOTF);
        const float var  = qsum * (1.f / NTOTF) - mean * mean;
        const float a    = g0[tid] / sqrtf(var + EPSF);
        als[tid] = a; bls[tid] = be0[tid] - mean * a;
        sred[tid] = 0.f; s2red[tid] = 0.f;
    }
    __syncthreads();

    // per-lane BN coeffs for input channels k = kh*32 + quad*8 + j
    float alr[16], blr[16];
#pragma unroll
    for (int kh = 0; kh < 2; ++kh)
#pragma unroll
        for (int j = 0; j < 8; ++j) {
            alr[kh * 8 + j] = als[kh * 32 + quad * 8 + j];
            blr[kh * 8 + j] = bls[kh * 32 + quad * 8 + j];
        }

    short8 afr[4][2];
    floatx4 bias[4];
#pragma unroll
    for (int mt = 0; mt < 4; ++mt) {
        const float* wr = w1 + (size_t)(mt * 16 + ln15) * 64;
#pragma unroll
        for (int kh = 0; kh < 2; ++kh) {
            const float4* wp = (const float4*)(wr + kh * 32 + quad * 8);
            float4 wa = wp[0], wb = wp[1];
            short8 v;
            v[0] = (short)f2bfbits(wa.x); v[1] = (short)f2bfbits(wa.y);
            v[2] = (short)f2bfbits(wa.z); v[3] = (short)f2bfbits(wa.w);
            v[4] = (short)f2bfbits(wb.x); v[5] = (short)f2bfbits(wb.y);
            v[6] = (short)f2bfbits(wb.z); v[7] = (short)f2bfbits(wb.w);
            afr[mt][kh] = v;
        }
        bias[mt] = *reinterpret_cast<const floatx4*>(b1 + mt * 16 + quad * 4);
    }

    float s[4][4] = {}, s2[4][4] = {};
#pragma unroll 2
    for (int nt = 0; nt < 4; ++nt) {
        const int pos = pbase + nt * 16 + ln15;
        const short8 h0 = *reinterpret_cast<const short8*>(&Hin[(size_t)pos * 64 + quad * 8]);
        const short8 h1 = *reinterpret_cast<const short8*>(&Hin[(size_t)pos * 64 + 32 + quad * 8]);
        short8 bf0, bf1;
#pragma unroll
        for (int j = 0; j < 8; ++j) {
            bf0[j] = (short)f2bfbits(relu_f(alr[j] * bfbits2f((unsigned short)h0[j]) + blr[j]));
            bf1[j] = (short)f2bfbits(relu_f(alr[8 + j] * bfbits2f((unsigned short)h1[j]) + blr[8 + j]));
        }
#pragma unroll
        for (int mt = 0; mt < 4; ++mt) {
            floatx4 c = {0.f, 0.f, 0.f, 0.f};
            c = __builtin_amdgcn_mfma_f32_16x16x32_bf16(afr[mt][0], bf0, c, 0, 0, 0);
            c = __builtin_amdgcn_mfma_f32_16x16x32_bf16(afr[mt][1], bf1, c, 0, 0, 0);
            uint2 o;
            float h0v = c[0] + bias[mt][0], h1v = c[1] + bias[mt][1];
            float h2v = c[2] + bias[mt][2], h3v = c[3] + bias[mt][3];
            s[mt][0] += h0v; s2[mt][0] += h0v * h0v;
            s[mt][1] += h1v; s2[mt][1] += h1v * h1v;
            s[mt][2] += h2v; s2[mt][2] += h2v * h2v;
            s[mt][3] += h3v; s2[mt][3] += h3v * h3v;
            o.x = (unsigned int)f2bfbits(h0v) | ((unsigned int)f2bfbits(h1v) << 16);
            o.y = (unsigned int)f2bfbits(h2v) | ((unsigned int)f2bfbits(h3v) << 16);
            *reinterpret_cast<uint2*>(&Hout[(size_t)pos * 64 + mt * 16 + quad * 4]) = o;
        }
    }
#pragma unroll
    for (int mt = 0; mt < 4; ++mt)
#pragma unroll
        for (int rg = 0; rg < 4; ++rg) {
            s[mt][rg]  += __shfl_xor(s[mt][rg], 1, 64);  s[mt][rg]  += __shfl_xor(s[mt][rg], 2, 64);
            s[mt][rg]  += __shfl_xor(s[mt][rg], 4, 64);  s[mt][rg]  += __shfl_xor(s[mt][rg], 8, 64);
            s2[mt][rg] += __shfl_xor(s2[mt][rg], 1, 64); s2[mt][rg] += __shfl_xor(s2[mt][rg], 2, 64);
            s2[mt][rg] += __shfl_xor(s2[mt][rg], 4, 64); s2[mt][rg] += __shfl_xor(s2[mt][rg], 8, 64);
        }
    if (ln15 == 0) {
#pragma unroll
        for (int mt = 0; mt < 4; ++mt)
#pragma unroll
            for (int rg = 0; rg < 4; ++rg) {
                atomicAdd(&sred[mt * 16 + quad * 4 + rg], s[mt][rg]);
                atomicAdd(&s2red[mt * 16 + quad * 4 + rg], s2[mt][rg]);
            }
    }
    __syncthreads();
    const int rep = (blockIdx.x & (NREP - 1)) * 512;
    if (tid < 64) {
        unsafeAtomicAdd(&stats[rep + 128 + tid], sred[tid]);
        unsafeAtomicAdd(&stats[rep + 192 + tid], s2red[tid]);
    }
}

// ---------------------------------------------------------------------------
// K3: conv2 64->128, round-3 orientation (A = data: max over positions stays
// in-register/2-shfl). Barrier-free loads with BN1+relu in registers;
// max/min monotone-BN trick; stats replicated.
// ---------------------------------------------------------------------------
__global__ __launch_bounds__(256) void k_conv2(
    const unsigned short* __restrict__ H, const float* __restrict__ w2,
    const float* __restrict__ b2, const float* __restrict__ g1,
    const float* __restrict__ be1, float* __restrict__ rowmax,
    float* __restrict__ rowmin, float* __restrict__ stats)
{
    __shared__ float als[64], bls[64], sred[128], s2red[128];
    const int tid  = threadIdx.x;
    const int lane = tid & 63;
    const int wid  = tid >> 6;
    const int ln15 = lane & 15;
    const int quad = lane >> 4;
    const int r0   = blockIdx.x * 4;

    if (tid < 64) {
        float ssum = 0.f, qsum = 0.f;
#pragma unroll
        for (int r = 0; r < NREP; ++r) { ssum += stats[r * 512 + 128 + tid]; qsum += stats[r * 512 + 192 + tid]; }
        const float mean = ssum * (1.f / NTOTF);
        const float var  = qsum * (1.f / NTOTF) - mean * mean;
        const float a    = g1[tid] / sqrtf(var + EPSF);
        als[tid] = a; bls[tid] = be1[tid] - mean * a;
    }
    if (tid < 128) { sred[tid] = 0.f; s2red[tid] = 0.f; }
    __syncthreads();

    float alr[16], blr[16];
#pragma unroll
    for (int kh = 0; kh < 2; ++kh)
#pragma unroll
        for (int j = 0; j < 8; ++j) {
            alr[kh * 8 + j] = als[kh * 32 + quad * 8 + j];
            blr[kh * 8 + j] = bls[kh * 32 + quad * 8 + j];
        }

    const int chHalf = (wid & 1) * 64;
    short8 bfr[8];
    float bias[4];
#pragma unroll
    for (int nt = 0; nt < 4; ++nt) {
        const int n = chHalf + nt * 16 + ln15;
        bias[nt] = b2[n];
#pragma unroll
        for (int kh = 0; kh < 2; ++kh) {
            const float4* wp = (const float4*)&w2[(size_t)n * 64 + kh * 32 + quad * 8];
            float4 wa = wp[0], wb = wp[1];
            short8 v;
            v[0] = (short)f2bfbits(wa.x); v[1] = (short)f2bfbits(wa.y);
            v[2] = (short)f2bfbits(wa.z); v[3] = (short)f2bfbits(wa.w);
            v[4] = (short)f2bfbits(wb.x); v[5] = (short)f2bfbits(wb.y);
            v[6] = (short)f2bfbits(wb.z); v[7] = (short)f2bfbits(wb.w);
            bfr[nt * 2 + kh] = v;
        }
    }

    float s[4] = {0, 0, 0, 0}, s2[4] = {0, 0, 0, 0};
    for (int rr = 0; rr < 2; ++rr) {
        const int prow = r0 + (wid >> 1) * 2 + rr;
        float mx[4] = {-3.4e38f, -3.4e38f, -3.4e38f, -3.4e38f};
        float mn[4] = {3.4e38f, 3.4e38f, 3.4e38f, 3.4e38f};
#pragma unroll 2
        for (int mt = 0; mt < 4; ++mt) {
            const size_t rowb = (size_t)(prow * 64 + mt * 16 + ln15) * 64;
            const short8 h0 = *reinterpret_cast<const short8*>(&H[rowb + quad * 8]);
            const short8 h1 = *reinterpret_cast<const short8*>(&H[rowb + 32 + quad * 8]);
            short8 a0, a1;
#pragma unroll
            for (int j = 0; j < 8; ++j) {
                a0[j] = (short)f2bfbits(relu_f(alr[j] * bfbits2f((unsigned short)h0[j]) + blr[j]));
                a1[j] = (short)f2bfbits(relu_f(alr[8 + j] * bfbits2f((unsigned short)h1[j]) + blr[8 + j]));
            }
#pragma unroll
            for (int nt = 0; nt < 4; ++nt) {
                floatx4 a = {0.f, 0.f, 0.f, 0.f};
                a = __builtin_amdgcn_mfma_f32_16x16x32_bf16(a0, bfr[nt * 2 + 0], a, 0, 0, 0);
                a = __builtin_amdgcn_mfma_f32_16x16x32_bf16(a1, bfr[nt * 2 + 1], a, 0, 0, 0);
#pragma unroll
                for (int rg = 0; rg < 4; ++rg) {
                    const float h = a[rg] + bias[nt];
                    mx[nt] = fmaxf(mx[nt], h);
                    mn[nt] = fminf(mn[nt], h);
                    s[nt] += h; s2[nt] += h * h;
                }
            }
        }
#pragma unroll
        for (int nt = 0; nt < 4; ++nt) {
            mx[nt] = fmaxf(mx[nt], __shfl_xor(mx[nt], 16, 64));
            mx[nt] = fmaxf(mx[nt], __shfl_xor(mx[nt], 32, 64));
            mn[nt] = fminf(mn[nt], __shfl_xor(mn[nt], 16, 64));
            mn[nt] = fminf(mn[nt], __shfl_xor(mn[nt], 32, 64));
        }
        if (lane < 16) {
#pragma unroll
            for (int nt = 0; nt < 4; ++nt) {
                rowmax[(size_t)prow * 128 + chHalf + nt * 16 + lane] = mx[nt];
                rowmin[(size_t)prow * 128 + chHalf + nt * 16 + lane] = mn[nt];
            }
        }
    }
#pragma unroll
    for (int nt = 0; nt < 4; ++nt) {
        s[nt]  += __shfl_xor(s[nt], 16, 64);  s[nt]  += __shfl_xor(s[nt], 32, 64);
        s2[nt] += __shfl_xor(s2[nt], 16, 64); s2[nt] += __shfl_xor(s2[nt], 32, 64);
    }
    if (lane < 16) {
#pragma unroll
        for (int nt = 0; nt < 4; ++nt) {
            atomicAdd(&sred[chHalf + nt * 16 + ln15], s[nt]);
            atomicAdd(&s2red[chHalf + nt * 16 + ln15], s2[nt]);
        }
    }
    __syncthreads();
    const int rep = (blockIdx.x & (NREP - 1)) * 512;
    if (tid < 128) {
        unsafeAtomicAdd(&stats[rep + 256 + tid], sred[tid]);
        unsafeAtomicAdd(&stats[rep + 384 + tid], s2red[tid]);
    }
}

// ---------------------------------------------------------------------------
// K4: finalize BN2 + epilogue
// ---------------------------------------------------------------------------
__global__ __launch_bounds__(256) void k_out(
    const float* __restrict__ rowmax, const float* __restrict__ rowmin,
    const float* __restrict__ g2, const float* __restrict__ be2,
    const float* __restrict__ stats, float* __restrict__ out)
{
    __shared__ float als[128], bls[128];
    const int tid = threadIdx.x;
    if (tid < 128) {
        float ssum = 0.f, qsum = 0.f;
#pragma unroll
        for (int r = 0; r < NREP; ++r) { ssum += stats[r * 512 + 256 + tid]; qsum += stats[r * 512 + 384 + tid]; }
        const float mean = ssum * (1.f / NTOTF);
        const float var  = qsum * (1.f / NTOTF) - mean * mean;
        const float a    = g2[tid] / sqrtf(var + EPSF);
        als[tid] = a; bls[tid] = be2[tid] - mean * a;
    }
    __syncthreads();
    const int idx = blockIdx.x * 256 + tid;
    const int o = idx & 127;
    const float a = als[o];
    const float v = (a > 0.f) ? rowmax[idx] : rowmin[idx];
    out[idx] = relu_f(a * v + bls[o]);
}

// ---------------------------------------------------------------------------
extern "C" void kernel_launch(void* const* d_in, const int* in_sizes, int n_in,
                              void* d_out, int out_size, void* d_ws, size_t ws_size,
                              hipStream_t stream)
{
    (void)in_sizes; (void)n_in; (void)out_size; (void)ws_size;
    const float* X   = (const float*)d_in[0];
    const float* w0  = (const float*)d_in[1];
    const float* b0  = (const float*)d_in[2];
    const float* g0  = (const float*)d_in[3];
    const float* be0 = (const float*)d_in[4];
    const float* w1  = (const float*)d_in[5];
    const float* b1  = (const float*)d_in[6];
    const float* g1  = (const float*)d_in[7];
    const float* be1 = (const float*)d_in[8];
    const float* w2  = (const float*)d_in[9];
    const float* b2  = (const float*)d_in[10];
    const float* g2  = (const float*)d_in[11];
    const float* be2 = (const float*)d_in[12];
    float* out = (float*)d_out;

    char* ws = (char*)d_ws;
    unsigned short* H = (unsigned short*)ws;                 // 134,217,728 B
    float* rowmax = (float*)(ws + 134217728);                // 8,388,608 B
    float* rowmin = (float*)(ws + 134217728 + 8388608);      // 8,388,608 B
    float* stats  = (float*)(ws + 134217728 + 2 * 8388608);  // NREP*512 floats

    hipMemsetAsync(stats, 0, NREP * 512 * sizeof(float), stream);
    hipLaunchKernelGGL(k_conv0, dim3(PTOT / 256), dim3(256), 0, stream, X, w0, b0, H, stats);
    hipLaunchKernelGGL(k_conv1, dim3(PTOT / 256), dim3(256), 0, stream, H, H, w1, b1, g0, be0, stats);
    hipLaunchKernelGGL(k_conv2, dim3(ROWS / 4), dim3(256), 0, stream, H, w2, b2, g1, be1, rowmax, rowmin, stats);
    hipLaunchKernelGGL(k_out, dim3(ROWS * 128 / 256), dim3(256), 0, stream, rowmax, rowmin, g2, be2, stats, out);
}